// Round 11
// baseline (299.460 us; speedup 1.0000x reference)
//
#include <hip/hip_runtime.h>
#include <math.h>

// ---------------------------------------------------------------------------
// Quantized CNN forward (bitwise-exact vs fp32 reference):
//   block_k: maxpool2( quant_act( conv3x3(x, quant_weight(wk)), ak ) )
//   then global max over HxW, then 1x1 conv (10x128).
//
// R25: R23/R24 scheduling+staging variants all lost to R19 (76us). Surviving
// model: per-entry overhead (decode/sign/addr ~5 VALU + walk + headers) is
// paid per 4 FMAs -> FMA:overhead ~ 1:1.8. This round AMORTIZES: each
// thread handles 2 pooled rows x 8 co (ty = tyy(0..7) row-pair + half(0..1)
// co-split; waves 0-1 = half 0, waves 2-3 = half 1, so all header reads
// stay wave-uniform). Per entry: 4 ds_read2 + 8 FMAs -> decode cost per FMA
// halves; per-thread header traffic halves (18 of 36 dwords). Total FMA and
// LDS-read volume unchanged.
// Row stride 40->42 (patch base 168*tyy: 168 mod 32 = 8 -> banks 8*tyy+tx
// cover 32 banks exactly 2-way = free; 160 would be 4-way). Parity planes:
// even cols +0..16, odd +21..37; u0 = cil*1428 + 42*kr + (kc&1?21:0) +
// (kc>>1); partner delta -20 (kc odd) / +21 (kc even).
// Staging, prefetch placement (before sync2), sync structure, entry order
// (chunk asc, cil asc, k asc per accumulator) byte-identical to verified
// R19 -> bitwise-same output.
// ---------------------------------------------------------------------------

__global__ __launch_bounds__(64)
void prep_zero(unsigned* __restrict__ maxb) {
    if (threadIdx.x < 4) maxb[threadIdx.x] = 0u;
}

__global__ __launch_bounds__(256)
void prep_absmax(const float* __restrict__ w1, const float* __restrict__ w2,
                 const float* __restrict__ w3, const float* __restrict__ wc,
                 unsigned* __restrict__ maxb) {
    const float* srcs[4] = {w1, w2, w3, wc};
    const int    ns[4]   = {32*3*9, 64*32*9, 128*64*9, 10*128};
    const int t = blockIdx.y;
    const float* s = srcs[t];
    const int    N = ns[t];
    float m = 0.f;
    for (int i = blockIdx.x * 256 + threadIdx.x; i < N; i += 16 * 256)
        m = fmaxf(m, fabsf(s[i]));
    #pragma unroll
    for (int o = 32; o > 0; o >>= 1) m = fmaxf(m, __shfl_down(m, o));
    __shared__ float red[4];
    const int lane = threadIdx.x & 63, wid = threadIdx.x >> 6;
    if (lane == 0) red[wid] = m;
    __syncthreads();
    if (threadIdx.x == 0) {
        float mm = fmaxf(fmaxf(red[0], red[1]), fmaxf(red[2], red[3]));
        atomicMax(maxb + t, __float_as_uint(mm));  // |w|>=0: uint order == float order
    }
}

// Classifier weights still need real quantized values (ternary * s).
__global__ __launch_bounds__(256)
void prep_qwc(const float* __restrict__ wc, const unsigned* __restrict__ maxb,
              float* __restrict__ qwc) {
    const float sc = fmaxf(__uint_as_float(maxb[3]), 1e-8f);
    const int i = blockIdx.x * 256 + threadIdx.x;
    if (i < 1280) qwc[i] = rintf(wc[i] / sc) * sc;
}

// Compacted nz-tap lists. Per (grp-of-16-co, chunk-of-4-ci) a 36-dword
// header: dwords 0..3 = 16 u8 counts; dwords 4..35 = per-co 4 inline u16
// entries (co c at halfwords 8+4c .. 8+4c+3).
// Entry = sign<<15 | (kc&1)<<14 | u0, with (stride-42 parity mapping)
//   u0 = cil*1428 + 42*(k/3) + ((k%3)&1 ? 21 : 0) + ((k%3)>>1)  (max 4390)
// Entries j>=4 go to pool[(rc*16+c)*32 + (j-4)] (capacity 32; 4+32=36 max).
// Order within a co: cil asc, k asc == the verified accumulation order.
__global__ __launch_bounds__(256)
void build_lists(const float* __restrict__ w1, const float* __restrict__ w2,
                 const float* __restrict__ w3, const unsigned* __restrict__ maxb,
                 unsigned* __restrict__ h1, unsigned short* __restrict__ p1,
                 unsigned* __restrict__ h2, unsigned short* __restrict__ p2,
                 unsigned* __restrict__ h3, unsigned short* __restrict__ p3) {
    const float* wsrc[3] = {w1, w2, w3};
    unsigned*       hs[3] = {h1, h2, h3};
    unsigned short* ps[3] = {p1, p2, p3};
    const int cins[3] = {3, 32, 64};
    const int nch[3]  = {1, 8, 16};
    const int ngc[3]  = {2, 32, 128};       // (Co/16) * nchunk
    const int t = blockIdx.y;
    const float* w = wsrc[t];
    const int CIN = cins[t], NCHUNK = nch[t];
    const int total = ngc[t] * 16;
    const float sc = fmaxf(__uint_as_float(maxb[t]), 1e-8f);
    for (int u = blockIdx.x * 256 + threadIdx.x; u < total; u += 8 * 256) {
        const int c = u & 15, rc = u >> 4;  // rc = grp*NCHUNK + ch
        const int ch = rc % NCHUNK, grp = rc / NCHUNK;
        const int co = grp * 16 + c;
        unsigned* hdr = hs[t] + (size_t)rc * 36;
        unsigned short* inl = (unsigned short*)(hdr + 4);
        unsigned short* ovf = ps[t] + ((size_t)rc * 16 + c) * 32;
        int j = 0;
        for (int cil = 0; cil < 4; ++cil) {
            const int ci = ch * 4 + cil;
            if (ci >= CIN) break;
            for (int k = 0; k < 9; ++k) {
                const float q = rintf(w[(co * CIN + ci) * 9 + k] / sc);
                unsigned sgn;
                if (q > 0.5f)       sgn = 0u;
                else if (q < -0.5f) sgn = 0x8000u;
                else continue;
                const int kr = k / 3, kc = k % 3;
                const unsigned u0 =
                    (unsigned)(cil * 1428 + kr * 42
                               + ((kc & 1) ? 21 : 0) + (kc >> 1));
                const unsigned short e =
                    (unsigned short)(sgn | ((unsigned)(kc & 1) << 14) | u0);
                if (j < 4) inl[c * 4 + j] = e;
                else       ovf[j - 4] = e;
                ++j;
            }
        }
        ((unsigned char*)hdr)[c] = (unsigned char)j;
    }
}

// Load one entry's 4x2 conv patch (rows kr..kr+3, both col parities) and
// apply 8 FMAs. Constant offsets -> ds_read2_b32 pairs (0/42, 84/126).
#define APPLY_ENTRY(e)                                                     \
    {                                                                      \
        const float wv = ((e) & 0x8000u) ? sNeg : sPos;   /* s_cselect */  \
        const float* pq0 = TB + ((e) & 0x3fffu);          /* v_add    */   \
        const float* pq1 = pq0 + (((e) & 0x4000u) ? -20 : 21);             \
        acc[cl][0] = fmaf(wv, pq0[0],   acc[cl][0]);                       \
        acc[cl][1] = fmaf(wv, pq1[0],   acc[cl][1]);                       \
        acc[cl][2] = fmaf(wv, pq0[42],  acc[cl][2]);                       \
        acc[cl][3] = fmaf(wv, pq1[42],  acc[cl][3]);                       \
        acc[cl][4] = fmaf(wv, pq0[84],  acc[cl][4]);                       \
        acc[cl][5] = fmaf(wv, pq1[84],  acc[cl][5]);                       \
        acc[cl][6] = fmaf(wv, pq0[126], acc[cl][6]);                       \
        acc[cl][7] = fmaf(wv, pq1[126], acc[cl][7]);                       \
    }

// Sparse fused conv3x3(pad=1) + maxpool2 + quant_act.
// 16x16 threads over a 16x16 pooled tile (32x32 conv px, 34x34 input tile).
// Thread (tx, ty): tyy = ty&7 -> pooled rows 2tyy..2tyy+1 (conv rows
// 4tyy..4tyy+3); half = ty>>3 -> co subset half*8..half*8+7 of the grp.
// ci in chunks of 4; staging reg-pipelined exactly as verified R19.
// Parity-split tile rows, stride 42 (patch reads 2-way/free on 32 banks).
template<int CIN, int Co, int LIDX>
__global__ __launch_bounds__(256, 3)
void conv_sparse(const float* __restrict__ in, const unsigned* __restrict__ hdrs,
                 const unsigned short* __restrict__ pool,
                 const unsigned* __restrict__ maxb,
                 const float* __restrict__ alpha_p, float* __restrict__ out,
                 int H, int W) {
    constexpr int NCHUNK = (CIN + 3) / 4;
    constexpr int CCH    = (CIN < 4) ? CIN : 4;
    constexpr int NGRP   = Co / 16;
    constexpr int PLANE  = 1428;               // 34 rows x 42 words
    const int PH = H >> 1, PW = W >> 1;
    const int tx = threadIdx.x, ty = threadIdx.y;
    const int tyy = ty & 7, half = ty >> 3;
    const int tid = ty * 16 + tx;
    const int b   = blockIdx.z / NGRP;
    const int grp = blockIdx.z % NGRP;
    const int px  = blockIdx.x * 16 + tx;
    const int py0 = blockIdx.y * 16 + 2 * tyy;
    const int ix0 = blockIdx.x * 32 - 1;
    const int iy0 = blockIdx.y * 32 - 1;

    __shared__ float tile[CCH * PLANE];
    const size_t HW = (size_t)H * W;
    const float* inB = in + (size_t)b * CIN * HW;

    // Flat staging slots hoisted once; -1 = zero-fill (pad / out of image).
    // pofs = physical (parity-split, stride 42) word offset of logical (r,c).
    int sidx[5], pofs[5];
    #pragma unroll
    for (int s = 0; s < 5; ++s) {
        const int idx = tid + 256 * s;
        const int r = idx / 34, c = idx - r * 34;
        const int gy = iy0 + r, gx = ix0 + c;
        sidx[s] = (idx < 1156 && gy >= 0 && gy < H && gx >= 0 && gx < W)
                  ? (gy * W + gx) : -1;
        pofs[s] = r * 42 + ((c & 1) ? 21 : 0) + (c >> 1);
    }

    float v[CCH][5];                              // in-flight staging buffer
    auto load_chunk = [&](int ch0) {
        #pragma unroll
        for (int ch = 0; ch < CCH; ++ch) {
            const float* inC = inB + (size_t)(ch0 + ch) * HW;
            #pragma unroll
            for (int s = 0; s < 5; ++s)
                v[ch][s] = (sidx[s] >= 0) ? inC[sidx[s]] : 0.f;
        }
    };
    auto store_tile = [&]() {
        #pragma unroll
        for (int ch = 0; ch < CCH; ++ch)
            #pragma unroll
            for (int s = 0; s < 5; ++s) {
                const int idx = tid + 256 * s;
                if (s < 4 || idx < 1156)
                    tile[ch * PLANE + pofs[s]] = v[ch][s];
            }
    };

    // +-s in SGPRs: exact (s = fmax(absmax,1e-8); -s = exact sign flip).
    const float sAbs = fmaxf(__uint_as_float(maxb[LIDX]), 1e-8f);
    const float sPos = __uint_as_float(__builtin_amdgcn_readfirstlane(__float_as_uint(sAbs)));
    const float sNeg = __uint_as_float(__builtin_amdgcn_readfirstlane(__float_as_uint(-sAbs)));

    float acc[8][8];                              // [co-in-half][conv row*2+par]
    #pragma unroll
    for (int cl = 0; cl < 8; ++cl)
        #pragma unroll
        for (int q = 0; q < 8; ++q) acc[cl][q] = 0.f;

    // Per-lane read base: logical conv row 4*tyy, even-col plane idx tx.
    // 168 mod 32 = 8 -> wave banks (8*tyy + tx) mod 32: exact 2-way (free).
    const float* TB = tile + 168 * tyy + tx;

    load_chunk(0);                                // prologue

    #pragma unroll 1
    for (int chunk = 0; chunk < NCHUNK; ++chunk) {
        // Half-header loads issued first (wave-uniform: half is per-wave).
        const unsigned* hdr = hdrs + (size_t)(grp * NCHUNK + chunk) * 36;
        unsigned cntd[2];
        #pragma unroll
        for (int i = 0; i < 2; ++i) cntd[i] = hdr[2 * half + i];
        unsigned ent[16];
        #pragma unroll
        for (int i = 0; i < 16; ++i) ent[i] = hdr[4 + 16 * half + i];

        __syncthreads();                          // sync1: tile free
        store_tile();                             // v -> tile (counted waits)
        if (chunk + 1 < NCHUNK) load_chunk((chunk + 1) * 4);  // issue early
        __syncthreads();                          // sync2: writes visible

        #pragma unroll
        for (int cl = 0; cl < 8; ++cl) {
            const unsigned cnt = (cntd[cl >> 2] >> ((cl & 3) * 8)) & 0xffu;
            if (!cnt) continue;                   // uniform pair skip
            #pragma unroll
            for (int j = 0; j < 4; ++j) {
                if ((int)cnt > j) {
                    const unsigned e =
                        (ent[2 * cl + (j >> 1)] >> ((j & 1) * 16)) & 0xffffu;
                    APPLY_ENTRY(e);
                }
            }
            if (cnt > 4) {                        // rare
                const unsigned short* pp =
                    pool + ((size_t)(grp * NCHUNK + chunk) * 16
                            + 8 * half + cl) * 32;
                #pragma unroll 1
                for (int j = 4; j < (int)cnt; ++j) {
                    const unsigned e = pp[j - 4];
                    APPLY_ENTRY(e);
                }
            }
        }
    }

    if (px < PW) {
        const float alpha = *alpha_p;
        const float scale = alpha / 3.0f;         // 2^ABITS - 1 = 3
        #pragma unroll
        for (int cl = 0; cl < 8; ++cl) {
            float* ob = out + ((size_t)b * Co + grp * 16 + half * 8 + cl)
                              * PH * PW;
            #pragma unroll
            for (int j = 0; j < 2; ++j) {
                const int py = py0 + j;
                if (py < PH) {
                    const float m =
                        fmaxf(fmaxf(acc[cl][4*j+0], acc[cl][4*j+1]),
                              fmaxf(acc[cl][4*j+2], acc[cl][4*j+3]));
                    const float y = fminf(fmaxf(m, 0.f), alpha);
                    ob[(size_t)py * PW + px] = rintf(y / scale) * scale;
                }
            }
        }
    }
}

// One wave per (channel, batch): global max over 28x28.
__global__ __launch_bounds__(64)
void gmax_kernel(const float* __restrict__ h3, float* __restrict__ g) {
    const int c = blockIdx.x, b = blockIdx.y;
    const float* p = h3 + ((size_t)b * 128 + c) * 784;
    float m = -INFINITY;
    for (int i = threadIdx.x; i < 784; i += 64) m = fmaxf(m, p[i]);
    #pragma unroll
    for (int o = 32; o > 0; o >>= 1) m = fmaxf(m, __shfl_down(m, o));
    if (threadIdx.x == 0) g[b * 128 + c] = m;
}

// 1x1 conv 128->10 per batch (same k-ascending FMA order as round 1).
__global__ __launch_bounds__(128)
void classify_kernel(const float* __restrict__ g, const float* __restrict__ qwc,
                     float* __restrict__ out) {
    const int b = blockIdx.x;
    __shared__ float gg[128];
    gg[threadIdx.x] = g[b * 128 + threadIdx.x];
    __syncthreads();
    if (threadIdx.x < 10) {
        float s = 0.f;
        for (int k = 0; k < 128; ++k) s += qwc[threadIdx.x * 128 + k] * gg[k];
        out[b * 10 + threadIdx.x] = s;
    }
}

extern "C" void kernel_launch(void* const* d_in, const int* in_sizes, int n_in,
                              void* d_out, int out_size, void* d_ws, size_t ws_size,
                              hipStream_t stream) {
    const float* x  = (const float*)d_in[0];
    const float* w1 = (const float*)d_in[1];
    const float* w2 = (const float*)d_in[2];
    const float* w3 = (const float*)d_in[3];
    const float* wc = (const float*)d_in[4];
    const float* a1 = (const float*)d_in[5];
    const float* a2 = (const float*)d_in[6];
    const float* a3 = (const float*)d_in[7];

    float* ws = (float*)d_ws;
    size_t o = 0;
    float*    qwc  = ws + o; o += 1280;
    unsigned* maxb = (unsigned*)(ws + o); o += 4;
    float*    g    = ws + o; o += 32 * 128;
    unsigned*       h1 = (unsigned*)(ws + o);       o += 2   * 36;   // hdrs
    unsigned short* p1 = (unsigned short*)(ws + o); o += 2   * 16 * 16;  // 32 hw/co
    unsigned*       h2 = (unsigned*)(ws + o);       o += 32  * 36;
    unsigned short* p2 = (unsigned short*)(ws + o); o += 32  * 16 * 16;
    unsigned*       h3 = (unsigned*)(ws + o);       o += 128 * 36;
    unsigned short* p3 = (unsigned short*)(ws + o); o += 128 * 16 * 16;
    float* h1p = ws + o; o += (size_t)32 * 32 * 112 * 112;
    float* h2p = ws + o; o += (size_t)32 * 64 * 56 * 56;
    float* h3p = ws + o; o += (size_t)32 * 128 * 28 * 28;

    prep_zero<<<1, 64, 0, stream>>>(maxb);
    prep_absmax<<<dim3(16, 4), 256, 0, stream>>>(w1, w2, w3, wc, maxb);
    prep_qwc<<<5, 256, 0, stream>>>(wc, maxb, qwc);
    build_lists<<<dim3(8, 3), 256, 0, stream>>>(w1, w2, w3, maxb,
                                                h1, p1, h2, p2, h3, p3);

    // conv1: 3->32, 224x224 -> pooled 112x112. tiles 7x7, z = 32b * 2 grp
    conv_sparse<3, 32, 0><<<dim3(7, 7, 32 * 2), dim3(16, 16), 0, stream>>>(
        x, h1, p1, maxb, a1, h1p, 224, 224);
    // conv2: 32->64, pooled 56x56. tiles 4x4, z = 32b * 4 grp
    conv_sparse<32, 64, 1><<<dim3(4, 4, 32 * 4), dim3(16, 16), 0, stream>>>(
        h1p, h2, p2, maxb, a2, h2p, 112, 112);
    // conv3: 64->128, pooled 28x28. tiles 2x2, z = 32b * 8 grp
    conv_sparse<64, 128, 2><<<dim3(2, 2, 32 * 8), dim3(16, 16), 0, stream>>>(
        h2p, h3, p3, maxb, a3, h3p, 56, 56);

    gmax_kernel<<<dim3(128, 32), 64, 0, stream>>>(h3p, g);
    classify_kernel<<<32, 128, 0, stream>>>(g, qwc, (float*)d_out);
}

// Round 12
// 250.123 us; speedup vs baseline: 1.1973x; 1.1973x over previous
//
#include <hip/hip_runtime.h>
#include <math.h>

// ---------------------------------------------------------------------------
// Quantized CNN forward (bitwise-exact vs fp32 reference):
//   block_k: maxpool2( quant_act( conv3x3(x, quant_weight(wk)), ak ) )
//   then global max over HxW, then 1x1 conv (10x128).
//
// R26: six structural experiments (R20-R25: DMA staging x2, raw-barrier
// pipeline, pair read-ahead, float2 staging, 8co-amortize) all lost to the
// R18 structure (76us convs, 254.8us total). Both pipes ~50%, nothing
// saturated: robust local minimum. This round REVERTS to R18 byte-for-byte
// in the conv path and removes pure work instead:
//   FUSE global-max into conv3's epilogue; delete gmax_kernel and h3p.
//   - max is order-independent and bit-exact (fmaxf assoc/comm; values >=0
//     after clip -> no -0/NaN; uint order == float order for >=0).
//   - per-thread quantized pooled value (invalid threads contribute 0.0,
//     safe: all values >=0) -> 64-lane shfl_down max per co -> 4-wave LDS
//     reduce -> one atomicMax(uint) per (block, co) into pre-zeroed g.
//   - saves 12.8MB write + 12.8MB read + one launch; costs ~200 VALU once
//     per conv3 block.
// ---------------------------------------------------------------------------

__global__ __launch_bounds__(256)
void prep_zero(unsigned* __restrict__ maxb, float* __restrict__ g) {
    const int i = blockIdx.x * 256 + threadIdx.x;
    if (i < 4) maxb[i] = 0u;
    if (i < 4096) g[i] = 0.f;                     // all outputs >= 0
}

__global__ __launch_bounds__(256)
void prep_absmax(const float* __restrict__ w1, const float* __restrict__ w2,
                 const float* __restrict__ w3, const float* __restrict__ wc,
                 unsigned* __restrict__ maxb) {
    const float* srcs[4] = {w1, w2, w3, wc};
    const int    ns[4]   = {32*3*9, 64*32*9, 128*64*9, 10*128};
    const int t = blockIdx.y;
    const float* s = srcs[t];
    const int    N = ns[t];
    float m = 0.f;
    for (int i = blockIdx.x * 256 + threadIdx.x; i < N; i += 16 * 256)
        m = fmaxf(m, fabsf(s[i]));
    #pragma unroll
    for (int o = 32; o > 0; o >>= 1) m = fmaxf(m, __shfl_down(m, o));
    __shared__ float red[4];
    const int lane = threadIdx.x & 63, wid = threadIdx.x >> 6;
    if (lane == 0) red[wid] = m;
    __syncthreads();
    if (threadIdx.x == 0) {
        float mm = fmaxf(fmaxf(red[0], red[1]), fmaxf(red[2], red[3]));
        atomicMax(maxb + t, __float_as_uint(mm));  // |w|>=0: uint order == float order
    }
}

// Classifier weights still need real quantized values (ternary * s).
__global__ __launch_bounds__(256)
void prep_qwc(const float* __restrict__ wc, const unsigned* __restrict__ maxb,
              float* __restrict__ qwc) {
    const float sc = fmaxf(__uint_as_float(maxb[3]), 1e-8f);
    const int i = blockIdx.x * 256 + threadIdx.x;
    if (i < 1280) qwc[i] = rintf(wc[i] / sc) * sc;
}

// Compacted nz-tap lists. Per (grp-of-16-co, chunk-of-4-ci) a 36-dword
// header: dwords 0..3 = 16 u8 counts; dwords 4..35 = per-co 4 inline u16
// entries (co c at halfwords 8+4c .. 8+4c+3). Entry = sign<<15 | word_off,
// word_off = cil*1156 + (k/3)*34 + (k%3)  (max 3538 < 0x8000).
// Entries j>=4 go to pool[(rc*16+c)*32 + (j-4)] (capacity 32; 4+32=36 max).
// Order within a co: cil asc, k asc == the verified accumulation order.
__global__ __launch_bounds__(256)
void build_lists(const float* __restrict__ w1, const float* __restrict__ w2,
                 const float* __restrict__ w3, const unsigned* __restrict__ maxb,
                 unsigned* __restrict__ h1, unsigned short* __restrict__ p1,
                 unsigned* __restrict__ h2, unsigned short* __restrict__ p2,
                 unsigned* __restrict__ h3, unsigned short* __restrict__ p3) {
    const float* wsrc[3] = {w1, w2, w3};
    unsigned*       hs[3] = {h1, h2, h3};
    unsigned short* ps[3] = {p1, p2, p3};
    const int cins[3] = {3, 32, 64};
    const int nch[3]  = {1, 8, 16};
    const int ngc[3]  = {2, 32, 128};       // (Co/16) * nchunk
    const int t = blockIdx.y;
    const float* w = wsrc[t];
    const int CIN = cins[t], NCHUNK = nch[t];
    const int total = ngc[t] * 16;
    const float sc = fmaxf(__uint_as_float(maxb[t]), 1e-8f);
    for (int u = blockIdx.x * 256 + threadIdx.x; u < total; u += 8 * 256) {
        const int c = u & 15, rc = u >> 4;  // rc = grp*NCHUNK + ch
        const int ch = rc % NCHUNK, grp = rc / NCHUNK;
        const int co = grp * 16 + c;
        unsigned* hdr = hs[t] + (size_t)rc * 36;
        unsigned short* inl = (unsigned short*)(hdr + 4);
        unsigned short* ovf = ps[t] + ((size_t)rc * 16 + c) * 32;
        int j = 0;
        for (int cil = 0; cil < 4; ++cil) {
            const int ci = ch * 4 + cil;
            if (ci >= CIN) break;
            for (int k = 0; k < 9; ++k) {
                const float q = rintf(w[(co * CIN + ci) * 9 + k] / sc);
                unsigned sgn;
                if (q > 0.5f)       sgn = 0u;
                else if (q < -0.5f) sgn = 0x8000u;
                else continue;
                const unsigned off = (unsigned)(cil * 1156 + (k / 3) * 34 + (k % 3));
                const unsigned short e = (unsigned short)(sgn | off);
                if (j < 4) inl[c * 4 + j] = e;
                else       ovf[j - 4] = e;
                ++j;
            }
        }
        ((unsigned char*)hdr)[c] = (unsigned char)j;
    }
}

// Sparse fused conv3x3(pad=1) + maxpool2 + quant_act.
// 16x16 threads over a 16x16 pooled tile (32x32 conv px, 34x34 input tile).
// ci in chunks of 4; staging PIPELINED through registers (R17/R18-verified).
// Compute: per co, walk the compacted entry list; each entry carries its
// LDS word-offset, so the 2x2 patch values are read directly (q[0],q[1],
// q[34],q[35]) with no tap scan and no weight loads.
// LIDX==2 (conv3): epilogue reduces the block's quantized pooled values to
// per-co maxima and atomicMax's into g (no h3 tensor, no gmax kernel).
template<int CIN, int Co, int LIDX>
__global__ __launch_bounds__(256, 4)
void conv_sparse(const float* __restrict__ in, const unsigned* __restrict__ hdrs,
                 const unsigned short* __restrict__ pool,
                 const unsigned* __restrict__ maxb,
                 const float* __restrict__ alpha_p, float* __restrict__ out,
                 int H, int W) {
    constexpr int NCHUNK = (CIN + 3) / 4;
    constexpr int CCH    = (CIN < 4) ? CIN : 4;
    constexpr int NGRP   = Co / 16;
    const int PH = H >> 1, PW = W >> 1;
    const int tx = threadIdx.x, ty = threadIdx.y;
    const int tid = ty * 16 + tx;
    const int b   = blockIdx.z / NGRP;
    const int grp = blockIdx.z % NGRP;
    const int px  = blockIdx.x * 16 + tx;
    const int py  = blockIdx.y * 16 + ty;
    const int ix0 = blockIdx.x * 32 - 1;
    const int iy0 = blockIdx.y * 32 - 1;

    __shared__ float tile[CCH * 1156];           // chunk-local [cil][34*34] flat
    const size_t HW = (size_t)H * W;
    const float* inB = in + (size_t)b * CIN * HW;

    // Flat staging slots hoisted once; -1 = zero-fill (pad / out of image).
    int sidx[5];
    #pragma unroll
    for (int s = 0; s < 5; ++s) {
        const int idx = tid + 256 * s;
        const int r = idx / 34, c = idx - r * 34;
        const int gy = iy0 + r, gx = ix0 + c;
        sidx[s] = (idx < 1156 && gy >= 0 && gy < H && gx >= 0 && gx < W)
                  ? (gy * W + gx) : -1;
    }

    float v[CCH][5];                              // in-flight staging buffer
    auto load_chunk = [&](int ch0) {
        #pragma unroll
        for (int ch = 0; ch < CCH; ++ch) {
            const float* inC = inB + (size_t)(ch0 + ch) * HW;
            #pragma unroll
            for (int s = 0; s < 5; ++s)
                v[ch][s] = (sidx[s] >= 0) ? inC[sidx[s]] : 0.f;
        }
    };
    auto store_tile = [&]() {
        #pragma unroll
        for (int ch = 0; ch < CCH; ++ch)
            #pragma unroll
            for (int s = 0; s < 5; ++s) {
                const int idx = tid + 256 * s;    // imm-offset ds_write
                if (s < 4 || idx < 1156) tile[ch * 1156 + idx] = v[ch][s];
            }
    };

    // +-s in SGPRs: exact (s = fmax(absmax,1e-8); -s = exact sign flip).
    const float sAbs = fmaxf(__uint_as_float(maxb[LIDX]), 1e-8f);
    const float sPos = __uint_as_float(__builtin_amdgcn_readfirstlane(__float_as_uint(sAbs)));
    const float sNeg = __uint_as_float(__builtin_amdgcn_readfirstlane(__float_as_uint(-sAbs)));

    float acc[16][4];
    #pragma unroll
    for (int c = 0; c < 16; ++c)
        #pragma unroll
        for (int q = 0; q < 4; ++q) acc[c][q] = 0.f;

    const int base = (2 * ty) * 34 + 2 * tx;     // lane's patch origin (words)

    load_chunk(0);                                // prologue

    #pragma unroll 1
    for (int chunk = 0; chunk < NCHUNK; ++chunk) {
        // Issue header loads FIRST: uniform address -> s_load; latency
        // hides behind the staging barriers below.
        const unsigned* hdr = hdrs + (size_t)(grp * NCHUNK + chunk) * 36;
        unsigned cntd[4];
        #pragma unroll
        for (int i = 0; i < 4; ++i) cntd[i] = hdr[i];
        unsigned ent[32];
        #pragma unroll
        for (int i = 0; i < 32; ++i) ent[i] = hdr[4 + i];

        __syncthreads();                          // tile free (prev compute done)
        store_tile();                             // v holds this chunk (aged)
        if (chunk + 1 < NCHUNK) load_chunk((chunk + 1) * 4);  // issue early
        __syncthreads();                          // writes visible

        const float* tb = tile + base;

        #pragma unroll
        for (int c = 0; c < 16; ++c) {
            const unsigned cnt = (cntd[c >> 2] >> ((c & 3) * 8)) & 0xffu;
            if (!cnt) continue;                   // uniform skip (~60% of co)
            #pragma unroll
            for (int j = 0; j < 4; ++j) {
                if ((int)cnt > j) {
                    const unsigned e = (ent[2 * c + (j >> 1)] >> ((j & 1) * 16)) & 0xffffu;
                    const float wv = (e & 0x8000u) ? sNeg : sPos;   // s_cselect
                    const float* q = tb + (e & 0x7fffu);            // v_add
                    acc[c][0] = fmaf(wv, q[0],  acc[c][0]);
                    acc[c][1] = fmaf(wv, q[1],  acc[c][1]);
                    acc[c][2] = fmaf(wv, q[34], acc[c][2]);
                    acc[c][3] = fmaf(wv, q[35], acc[c][3]);
                }
            }
            if (cnt > 4) {                        // rare (~1% of co)
                const unsigned short* pp =
                    pool + ((size_t)(grp * NCHUNK + chunk) * 16 + c) * 32;
                #pragma unroll 1
                for (int j = 4; j < (int)cnt; ++j) {
                    const unsigned e = pp[j - 4];
                    const float wv = (e & 0x8000u) ? sNeg : sPos;
                    const float* q = tb + (e & 0x7fffu);
                    acc[c][0] = fmaf(wv, q[0],  acc[c][0]);
                    acc[c][1] = fmaf(wv, q[1],  acc[c][1]);
                    acc[c][2] = fmaf(wv, q[34], acc[c][2]);
                    acc[c][3] = fmaf(wv, q[35], acc[c][3]);
                }
            }
        }
    }

    if constexpr (LIDX == 2) {
        // Fused global-max epilogue: out == g[32][128]. Values >= 0; max is
        // order-independent bit-exact; invalid threads contribute 0.0.
        const float alpha = *alpha_p;
        const float scale = alpha / 3.0f;         // 2^ABITS - 1 = 3
        const bool valid = (py < PH) && (px < PW);
        float mv[16];
        #pragma unroll
        for (int c = 0; c < 16; ++c) {
            const float m = fmaxf(fmaxf(acc[c][0], acc[c][1]),
                                  fmaxf(acc[c][2], acc[c][3]));
            const float y = fminf(fmaxf(m, 0.f), alpha);
            const float q = rintf(y / scale) * scale;
            mv[c] = valid ? q : 0.f;
        }
        #pragma unroll
        for (int c = 0; c < 16; ++c)
            #pragma unroll
            for (int o = 32; o > 0; o >>= 1)
                mv[c] = fmaxf(mv[c], __shfl_down(mv[c], o));
        __shared__ float red[4][16];
        const int lane = tid & 63, wv = tid >> 6;
        if (lane == 0) {
            #pragma unroll
            for (int c = 0; c < 16; ++c) red[wv][c] = mv[c];
        }
        __syncthreads();
        if (tid < 16) {
            const float r = fmaxf(fmaxf(red[0][tid], red[1][tid]),
                                  fmaxf(red[2][tid], red[3][tid]));
            atomicMax((unsigned*)(out + (size_t)b * 128 + grp * 16 + tid),
                      __float_as_uint(r));        // >=0: uint order == float
        }
    } else if (py < PH && px < PW) {
        const float alpha = *alpha_p;
        const float scale = alpha / 3.0f;         // 2^ABITS - 1 = 3
        #pragma unroll
        for (int c = 0; c < 16; ++c) {
            const float m = fmaxf(fmaxf(acc[c][0], acc[c][1]),
                                  fmaxf(acc[c][2], acc[c][3]));
            const float y = fminf(fmaxf(m, 0.f), alpha);
            out[(((size_t)b * Co + grp * 16 + c) * PH + py) * PW + px] =
                rintf(y / scale) * scale;
        }
    }
}

// 1x1 conv 128->10 per batch (same k-ascending FMA order as round 1).
__global__ __launch_bounds__(128)
void classify_kernel(const float* __restrict__ g, const float* __restrict__ qwc,
                     float* __restrict__ out) {
    const int b = blockIdx.x;
    __shared__ float gg[128];
    gg[threadIdx.x] = g[b * 128 + threadIdx.x];
    __syncthreads();
    if (threadIdx.x < 10) {
        float s = 0.f;
        for (int k = 0; k < 128; ++k) s += qwc[threadIdx.x * 128 + k] * gg[k];
        out[b * 10 + threadIdx.x] = s;
    }
}

extern "C" void kernel_launch(void* const* d_in, const int* in_sizes, int n_in,
                              void* d_out, int out_size, void* d_ws, size_t ws_size,
                              hipStream_t stream) {
    const float* x  = (const float*)d_in[0];
    const float* w1 = (const float*)d_in[1];
    const float* w2 = (const float*)d_in[2];
    const float* w3 = (const float*)d_in[3];
    const float* wc = (const float*)d_in[4];
    const float* a1 = (const float*)d_in[5];
    const float* a2 = (const float*)d_in[6];
    const float* a3 = (const float*)d_in[7];

    float* ws = (float*)d_ws;
    size_t o = 0;
    float*    qwc  = ws + o; o += 1280;
    unsigned* maxb = (unsigned*)(ws + o); o += 4;
    float*    g    = ws + o; o += 32 * 128;
    unsigned*       h1 = (unsigned*)(ws + o);       o += 2   * 36;   // hdrs
    unsigned short* p1 = (unsigned short*)(ws + o); o += 2   * 16 * 16;  // 32 hw/co
    unsigned*       h2 = (unsigned*)(ws + o);       o += 32  * 36;
    unsigned short* p2 = (unsigned short*)(ws + o); o += 32  * 16 * 16;
    unsigned*       h3 = (unsigned*)(ws + o);       o += 128 * 36;
    unsigned short* p3 = (unsigned short*)(ws + o); o += 128 * 16 * 16;
    float* h1p = ws + o; o += (size_t)32 * 32 * 112 * 112;
    float* h2p = ws + o; o += (size_t)32 * 64 * 56 * 56;

    prep_zero<<<16, 256, 0, stream>>>(maxb, g);
    prep_absmax<<<dim3(16, 4), 256, 0, stream>>>(w1, w2, w3, wc, maxb);
    prep_qwc<<<5, 256, 0, stream>>>(wc, maxb, qwc);
    build_lists<<<dim3(8, 3), 256, 0, stream>>>(w1, w2, w3, maxb,
                                                h1, p1, h2, p2, h3, p3);

    // conv1: 3->32, 224x224 -> pooled 112x112. tiles 7x7, z = 32b * 2 grp
    conv_sparse<3, 32, 0><<<dim3(7, 7, 32 * 2), dim3(16, 16), 0, stream>>>(
        x, h1, p1, maxb, a1, h1p, 224, 224);
    // conv2: 32->64, pooled 56x56. tiles 4x4, z = 32b * 4 grp
    conv_sparse<32, 64, 1><<<dim3(4, 4, 32 * 4), dim3(16, 16), 0, stream>>>(
        h1p, h2, p2, maxb, a2, h2p, 112, 112);
    // conv3: 64->128, pooled 28x28, FUSED global-max -> g. tiles 2x2.
    conv_sparse<64, 128, 2><<<dim3(2, 2, 32 * 8), dim3(16, 16), 0, stream>>>(
        h2p, h3, p3, maxb, a3, g, 56, 56);

    classify_kernel<<<32, 128, 0, stream>>>(g, qwc, (float*)d_out);
}